// Round 6
// baseline (287.471 us; speedup 1.0000x reference)
//
#include <hip/hip_runtime.h>

typedef __attribute__((ext_vector_type(8))) short short8;   // 8 bf16 (4 VGPRs) MFMA A/B frag
typedef __attribute__((ext_vector_type(4))) float f32x4;    // MFMA C/D frag

constexpr int ITERS = 4;                         // row-tiles per block (contiguous)
constexpr int GRID  = 2048;                      // 8192 tiles / 4
constexpr float L2E2 = 2.8853900817779268f;      // 2*log2(e)

union V16 { uint4 u; short8 s; };

// round-half-up bf16 pair pack: (bits+0x8000)>>16, two elems -> one u32 via v_perm.
__device__ __forceinline__ unsigned pk(float lo, float hi) {
  const unsigned a = __float_as_uint(lo) + 0x8000u;
  const unsigned b = __float_as_uint(hi) + 0x8000u;
  return __builtin_amdgcn_perm(b, a, 0x07060302u);  // dst = [a.hi16, b.hi16]
}

__device__ __forceinline__ short8 pk8(f32x4 a, f32x4 b) {
  V16 v;
  v.u.x = pk(a[0], a[1]); v.u.y = pk(a[2], a[3]);
  v.u.z = pk(b[0], b[1]); v.u.w = pk(b[2], b[3]);
  return v.s;
}

// LDS-FREE, BARRIER-FREE ablation of the r0-r5 plateau (~78us fused, all pipes
// <50%, 4 waves/SIMD, per-wave issue ~12%): the only structural element never
// removed was the LDS-stage + __syncthreads coupling. It existed to feed B
// fragments -- but the mfma_f32_16x16x32_bf16 B-layout is lane-local
// CONTIGUOUS x: lane's frag = x[row = tile*64 + tt*16 + (lane&15)][k = q*8..+7]
// (verified against the staged version's chunk algebra). So x loads straight
// from global into frags: no LDS, no pack, no barriers; waves free-run with a
// depth-1 ping-pong prefetch; 8-wave re-read of each 16KB tile hits L1/L2.
//
// Mapping (r5): 512 threads, 8 waves, wave = classifier; lane keeps o of
// sub-tile tt==q -> all 64 lanes store one float (row = lane).
// Math (r4/r5, exact): out = rcp(exp2(P)+1); L2E2*b1 folded into MFMA C-init;
// per hidden-quad ONE rcp via 4-way fraction combining; quarter-bias P seed.
//
// launch_bounds stays (512,4): round 1 proved min-waves=8 clamps arch VGPRs
// to 32 and spills everything (833MB scratch traffic).
__global__ __launch_bounds__(512, 4) void fused_mlp8(
    const float* __restrict__ x, const float* __restrict__ W1,
    const float* __restrict__ b1, const float* __restrict__ W2,
    const float* __restrict__ b2, float* __restrict__ out) {

  const int tid  = threadIdx.x;
  const int wave = tid >> 6;        // classifier k = wave (K=8)
  const int lane = tid & 63;
  const int m16  = lane & 15;
  const int q    = lane >> 4;

  // per-lane x pointer: row m16 of the block's first tile, k-offset q*8.
  // step s = i*4+tt advances by 1024 floats (16 rows x 64).
  const float* xl = x + (long)blockIdx.x * (ITERS * 64 * 64) + m16 * 64 + q * 8;

  // ---- issue step-0 loads FIRST; W1/const setup hides their latency
  f32x4 ld[2][4];
#pragma unroll
  for (int c = 0; c < 2; ++c) {
    ld[0][2 * c]     = *(const f32x4*)(xl + c * 32);
    ld[0][2 * c + 1] = *(const f32x4*)(xl + c * 32 + 4);
  }

  // ---- W1 A-fragments (scaled by L2E2): this wave's classifier only.
  short8 w1f[2][2];
#pragma unroll
  for (int mt = 0; mt < 2; ++mt) {
    const int n = wave * 32 + mt * 16 + m16;
#pragma unroll
    for (int ks = 0; ks < 2; ++ks) {
      const float* p = W1 + n * 64 + ks * 32 + q * 8;
      const f32x4 u0 = *(const f32x4*)p, u1 = *(const f32x4*)(p + 4);
      f32x4 s0, s1;
#pragma unroll
      for (int r = 0; r < 4; ++r) { s0[r] = L2E2 * u0[r]; s1[r] = L2E2 * u1[r]; }
      w1f[mt][ks] = pk8(s0, s1);
    }
  }

  // ---- folded per-lane constants, hidden units n0 = wave*32 + mt*16 + q*4
  f32x4 kb1[2], w2q[2];
  float s = 0.f;
#pragma unroll
  for (int mt = 0; mt < 2; ++mt) {
    const int n0 = wave * 32 + mt * 16 + q * 4;
    const f32x4 b1x = *(const f32x4*)(b1 + n0);
    const f32x4 w2x = *(const f32x4*)(W2 + n0);
#pragma unroll
    for (int r = 0; r < 4; ++r) {
      kb1[mt][r] = L2E2 * b1x[r];
      w2q[mt][r] = (2.0f * L2E2) * w2x[r];
      s += w2x[r];
    }
  }
  s += __shfl_xor(s, 16);
  s += __shfl_xor(s, 32);
  const float KSbn = -0.25f * L2E2 * (s + b2[wave]);  // quarter-bias P seed

  float osel = 0.f;
#pragma unroll
  for (int st = 0; st < ITERS * 4; ++st) {       // fully unrolled: indices static
    const int i  = st >> 2;
    const int tt = st & 3;
    const int cur = st & 1;

    // ---- prefetch step st+1 into the other buffer (no barrier anywhere)
    if (st + 1 < ITERS * 4) {
      const float* gp = xl + (st + 1) * 1024;
#pragma unroll
      for (int c = 0; c < 2; ++c) {
        ld[cur ^ 1][2 * c]     = *(const f32x4*)(gp + c * 32);
        ld[cur ^ 1][2 * c + 1] = *(const f32x4*)(gp + c * 32 + 4);
      }
    }

    // ---- compute step st from ld[cur]
    const short8 xf0 = pk8(ld[cur][0], ld[cur][1]);   // k  0..31 (lane slice)
    const short8 xf1 = pk8(ld[cur][2], ld[cur][3]);   // k 32..63

    f32x4 acc[2];
#pragma unroll
    for (int mt = 0; mt < 2; ++mt) {
      f32x4 z = kb1[mt];   // bias pre-folded as MFMA C-init
      z = __builtin_amdgcn_mfma_f32_16x16x32_bf16(w1f[mt][0], xf0, z, 0, 0, 0);
      z = __builtin_amdgcn_mfma_f32_16x16x32_bf16(w1f[mt][1], xf1, z, 0, 0, 0);
      acc[mt] = z;
    }

    float P = KSbn;
#pragma unroll
    for (int mt = 0; mt < 2; ++mt) {
      // 4-way combined sum of w/(e+1): one rcp per hidden quad (exact)
      const float e0 = __builtin_amdgcn_exp2f(acc[mt][0]);
      const float e1 = __builtin_amdgcn_exp2f(acc[mt][1]);
      const float e2 = __builtin_amdgcn_exp2f(acc[mt][2]);
      const float e3 = __builtin_amdgcn_exp2f(acc[mt][3]);
      const float f0 = e0 + 1.0f, f1 = e1 + 1.0f;
      const float f2 = e2 + 1.0f, f3 = e3 + 1.0f;
      const float p01 = f0 * f1, p23 = f2 * f3;
      const float n01 = __builtin_fmaf(w2q[mt][0], f1, w2q[mt][1] * f0);
      const float n23 = __builtin_fmaf(w2q[mt][2], f3, w2q[mt][3] * f2);
      const float N   = __builtin_fmaf(n01, p23, n23 * p01);
      P = __builtin_fmaf(N, __builtin_amdgcn_rcpf(p01 * p23), P);
    }
    P += __shfl_xor(P, 16);
    P += __shfl_xor(P, 32);
    const float o = __builtin_amdgcn_rcpf(__builtin_amdgcn_exp2f(P) + 1.0f);
    osel = (tt == q) ? o : osel;   // lane keeps its own row's o

    // ---- end of tile: all 64 lanes store one float (row = lane, col = wave)
    if (tt == 3) {
      const long tile = (long)blockIdx.x * ITERS + i;
      out[(tile * 64 + lane) * 8 + wave] = osel;
    }
  }
}

extern "C" void kernel_launch(void* const* d_in, const int* in_sizes, int n_in,
                              void* d_out, int out_size, void* d_ws, size_t ws_size,
                              hipStream_t stream) {
  const float* x  = (const float*)d_in[0];
  const float* W1 = (const float*)d_in[1];
  const float* b1 = (const float*)d_in[2];
  const float* W2 = (const float*)d_in[3];
  const float* b2 = (const float*)d_in[4];
  float* out = (float*)d_out;
  fused_mlp8<<<GRID, 512, 0, stream>>>(x, W1, b1, W2, b2, out);
}

// Round 8
// 210.598 us; speedup vs baseline: 1.3650x; 1.3650x over previous
//
#include <hip/hip_runtime.h>

typedef __attribute__((ext_vector_type(8))) short short8;   // 8 bf16 (4 VGPRs) MFMA A/B frag
typedef __attribute__((ext_vector_type(4))) float f32x4;    // MFMA C/D frag

constexpr int NTILES = 8192;        // 524288 rows / 64
constexpr int GRID   = 1792;        // 7 blocks/CU x 256 CU: EXACT single-round residency
constexpr int PAIRS  = GRID / 2;    // 896 tile-streams; pair (2b,2b+1) share a stream
constexpr float L2E2 = 2.8853900817779268f;  // 2*log2(e)

union V16 { uint4 u; short8 s; };

// round-half-up bf16 pair pack: (bits+0x8000)>>16, two elems -> one u32 via v_perm.
__device__ __forceinline__ unsigned pk(float lo, float hi) {
  const unsigned a = __float_as_uint(lo) + 0x8000u;
  const unsigned b = __float_as_uint(hi) + 0x8000u;
  return __builtin_amdgcn_perm(b, a, 0x07060302u);  // dst = [a.hi16, b.hi16]
}

__device__ __forceinline__ V16 pk8(f32x4 a, f32x4 b) {
  V16 v;
  v.u.x = pk(a[0], a[1]); v.u.y = pk(a[2], a[3]);
  v.u.z = pk(b[0], b[1]); v.u.w = pk(b[2], b[3]);
  return v;
}

// SINGLE-ROUND GRID-STRIDE: the r0-r6 series fits time = ceil(block-rounds) x
// T_block with residency ~7 blocks/CU (per-wave granule ~64 arch + acc > 64
// total; floor(512/72)=7 waves/SIMD) -- every structure paid a 2x tail round.
// Fix: GRID=1792 (7/CU exactly), blocks grid-stride 9-10 tiles -> no rounds,
// no tail, setup amortized over 2.3x more tiles than r0.
// K-split keeps per-wave state small (1 classifier/wave, ~60 arch regs):
// khalf = blockIdx&1 is BLOCK-constant (so single constant set); pair-blocks
// (2b,2b+1) walk the same tile stream in lockstep -> 2nd x read is L2-hot.
//
// Per-tile pipeline (r0, proven): compute xb[p]; store; pack pf->xb[p^1];
// ONE barrier; prefetch pf <- tile s+2.
// Math (r4/r5, exact): out = rcp(exp2(P)+1); L2E2*b1 folded into MFMA C-init;
// per hidden-quad ONE rcp via 4-way fraction combining; quarter-bias P seed.
// launch_bounds stays (256,4): min-waves=8 clamps arch VGPRs to 32 and spills
// (round-1: 833MB scratch traffic, 3.6x slower).
__global__ __launch_bounds__(256, 4) void fused_mlp8(
    const float* __restrict__ x, const float* __restrict__ W1,
    const float* __restrict__ b1, const float* __restrict__ W2,
    const float* __restrict__ b2, float* __restrict__ out) {

  // x: 2 buffers x 64 rows x 8 chunks(16B); chunk c of row r at r*8 + (c ^ (r&7))
  __shared__ V16 xb[2][512];   // 16 KiB

  const int tid  = threadIdx.x;
  const int wave = tid >> 6;
  const int lane = tid & 63;
  const int m16  = lane & 15;
  const int q    = lane >> 4;

  const int khalf = blockIdx.x & 1;        // which 4 classifiers this block owns
  const int tbase = blockIdx.x >> 1;       // tile-stream id 0..895
  const int nt    = (NTILES - tbase + PAIRS - 1) / PAIRS;   // 9 or 10 tiles
  const int k     = khalf * 4 + wave;      // this wave's classifier

  // ---- staging geometry: thread covers row=tid>>2, cols seg*16..+15 (64B)
  const int srow = tid >> 2;
  const int seg  = tid & 3;
  const int sw   = srow & 7;
  const float* gbase = x + (long)srow * 64 + seg * 16;

  // ---- issue tile-0 loads FIRST; W1/const setup hides their latency
  f32x4 pf[4];
  {
    const float* gp = gbase + (long)tbase * 4096;
#pragma unroll
    for (int c = 0; c < 4; ++c) pf[c] = *(const f32x4*)(gp + c * 4);
  }

  // ---- W1 A-fragments (scaled by L2E2): classifier k only.
  short8 w1f[2][2];
#pragma unroll
  for (int mt = 0; mt < 2; ++mt) {
    const int n = k * 32 + mt * 16 + m16;
#pragma unroll
    for (int ks = 0; ks < 2; ++ks) {
      const float* p = W1 + n * 64 + ks * 32 + q * 8;
      const f32x4 u0 = *(const f32x4*)p, u1 = *(const f32x4*)(p + 4);
      f32x4 s0, s1;
#pragma unroll
      for (int r = 0; r < 4; ++r) { s0[r] = L2E2 * u0[r]; s1[r] = L2E2 * u1[r]; }
      w1f[mt][ks] = pk8(s0, s1).s;
    }
  }

  // ---- folded per-lane constants, hidden units n0 = k*32 + mt*16 + q*4
  f32x4 kb1[2], w2q[2];
  float s = 0.f;
#pragma unroll
  for (int mt = 0; mt < 2; ++mt) {
    const int n0 = k * 32 + mt * 16 + q * 4;
    const f32x4 b1x = *(const f32x4*)(b1 + n0);
    const f32x4 w2x = *(const f32x4*)(W2 + n0);
#pragma unroll
    for (int r = 0; r < 4; ++r) {
      kb1[mt][r] = L2E2 * b1x[r];
      w2q[mt][r] = (2.0f * L2E2) * w2x[r];
      s += w2x[r];
    }
  }
  s += __shfl_xor(s, 16);
  s += __shfl_xor(s, 32);
  const float KSbn = -0.25f * L2E2 * (s + b2[k]);  // quarter-bias P seed

  // ---- prologue: pack tile0 -> xb[0]; prefetch tile1 -> pf
  xb[0][srow * 8 + ((seg * 2)     ^ sw)] = pk8(pf[0], pf[1]);
  xb[0][srow * 8 + ((seg * 2 + 1) ^ sw)] = pk8(pf[2], pf[3]);
  if (nt > 1) {
    const float* gp = gbase + ((long)tbase + PAIRS) * 4096;
#pragma unroll
    for (int c = 0; c < 4; ++c) pf[c] = *(const f32x4*)(gp + c * 4);
  }
  __syncthreads();

  for (int i = 0; i < nt; ++i) {
    const int p = i & 1;
    const long tile = tbase + (long)i * PAIRS;

    // ---- compute tile i from xb[p]; lane keeps o of sub-tile tt==q
    float osel = 0.f;
#pragma unroll
    for (int tt = 0; tt < 4; ++tt) {
      const int r   = tt * 16 + m16;
      const int rsw = r & 7;
      const short8 xf0 = xb[p][r * 8 + (q       ^ rsw)].s;
      const short8 xf1 = xb[p][r * 8 + ((q + 4) ^ rsw)].s;

      f32x4 acc[2];
#pragma unroll
      for (int mt = 0; mt < 2; ++mt) {
        f32x4 z = kb1[mt];   // bias pre-folded as MFMA C-init
        z = __builtin_amdgcn_mfma_f32_16x16x32_bf16(w1f[mt][0], xf0, z, 0, 0, 0);
        z = __builtin_amdgcn_mfma_f32_16x16x32_bf16(w1f[mt][1], xf1, z, 0, 0, 0);
        acc[mt] = z;
      }

      float P = KSbn;
#pragma unroll
      for (int mt = 0; mt < 2; ++mt) {
        // 4-way combined sum of w/(e+1): one rcp per hidden quad (exact)
        const float e0 = __builtin_amdgcn_exp2f(acc[mt][0]);
        const float e1 = __builtin_amdgcn_exp2f(acc[mt][1]);
        const float e2 = __builtin_amdgcn_exp2f(acc[mt][2]);
        const float e3 = __builtin_amdgcn_exp2f(acc[mt][3]);
        const float f0 = e0 + 1.0f, f1 = e1 + 1.0f;
        const float f2 = e2 + 1.0f, f3 = e3 + 1.0f;
        const float p01 = f0 * f1, p23 = f2 * f3;
        const float n01 = __builtin_fmaf(w2q[mt][0], f1, w2q[mt][1] * f0);
        const float n23 = __builtin_fmaf(w2q[mt][2], f3, w2q[mt][3] * f2);
        const float N   = __builtin_fmaf(n01, p23, n23 * p01);
        P = __builtin_fmaf(N, __builtin_amdgcn_rcpf(p01 * p23), P);
      }
      P += __shfl_xor(P, 16);
      P += __shfl_xor(P, 32);
      const float o = __builtin_amdgcn_rcpf(__builtin_amdgcn_exp2f(P) + 1.0f);
      osel = (tt == q) ? o : osel;   // lane keeps its own row's o
    }

    // ---- all 64 lanes store one float: row = lane, col = classifier k
    out[(tile * 64 + lane) * 8 + k] = osel;

    // ---- pack tile i+1 regs -> xb[p^1] (pre-barrier)
    if (i + 1 < nt) {
      xb[p ^ 1][srow * 8 + ((seg * 2)     ^ sw)] = pk8(pf[0], pf[1]);
      xb[p ^ 1][srow * 8 + ((seg * 2 + 1) ^ sw)] = pk8(pf[2], pf[3]);
    }

    __syncthreads();   // the ONLY barrier per iteration

    // ---- issue tile i+2 loads; consumed at iteration i+1's pack
    if (i + 2 < nt) {
      const float* gp = gbase + (tile + 2 * PAIRS) * 4096;
#pragma unroll
      for (int c = 0; c < 4; ++c) pf[c] = *(const f32x4*)(gp + c * 4);
    }
  }
}

extern "C" void kernel_launch(void* const* d_in, const int* in_sizes, int n_in,
                              void* d_out, int out_size, void* d_ws, size_t ws_size,
                              hipStream_t stream) {
  const float* x  = (const float*)d_in[0];
  const float* W1 = (const float*)d_in[1];
  const float* b1 = (const float*)d_in[2];
  const float* W2 = (const float*)d_in[3];
  const float* b2 = (const float*)d_in[4];
  float* out = (float*)d_out;
  fused_mlp8<<<GRID, 256, 0, stream>>>(x, W1, b1, W2, b2, out);
}